// Round 3
// baseline (315.254 us; speedup 1.0000x reference)
//
#include <hip/hip_runtime.h>

// BondWeight: out[b, src+1, dst+1] = w; out[b, dst+1, src+1] = w (two passes,
// last-write-wins within the 1024-write per-batch sequence, numpy semantics).
// B=1024, E=512, T=8, N=256. Output 256 MB f32 -> pure HBM-write-bound.
//
// R6: STRUCTURAL SPLIT. R4 (address-phase rotation) and R5 (LDS-only barriers,
// stores free to pipeline across all chunks) were BOTH neutral at ~101 us
// kernel vs the ~43 us store floor -> the fused kernel's store stream drains
// at ~2.6 TB/s regardless of schedule. Remaining difference vs the 6.4 TB/s
// rocclr fill is the CONFIGURATION of the storing kernel: fill is 8-VGPR,
// no-LDS, 32 waves/CU of pure stores; ours is 16 waves/CU (32KB LDS cap)
// with stores interleaved 1:25 with LDS/VALU ops -> about half the
// outstanding-write concurrency per CU. Write BW scales with in-flight
// requests, not issue rate.
//
// FIX: split into
//   A) pure zero-stream kernel, cloned from the fill's shape (no LDS, tiny
//      VGPR, grid-stride float4) -> 32 waves/CU, expect ~42 us for 256 MB.
//   B) winner-resolve + scatter kernel: only ~1.5% of cells are nonzero.
//      One block per (batch, 64-row chunk); 32 KB LDS u16 CAS-max table
//      (identical last-write-wins packing as before); winners store single
//      dwords over A's zeros. ~10-20 us.
// Same-stream launch order makes A's zeros visible before B's stores.

#define NB_E 512
#define NB_N 256
#define CH_ROWS 64
#define CH_WORDS (CH_ROWS * NB_N / 2)   // 8192 u32 = 32 KB LDS

typedef float v4f __attribute__((ext_vector_type(4)));

// ---------------- Kernel A: pure zero stream (fill clone) ----------------
__global__ __launch_bounds__(256) void BondWeight_zero_kernel(
    float* __restrict__ out, int total4)
{
    v4f* __restrict__ o = (v4f*)out;
    const v4f z = {0.f, 0.f, 0.f, 0.f};
    const int stride = gridDim.x * 256;
    for (int k = blockIdx.x * 256 + threadIdx.x; k < total4; k += stride)
        o[k] = z;
}

// ---------------- Kernel B: resolve last-write-wins, scatter winners -----
__device__ __forceinline__ void lds_max_u16(unsigned int* tab, int cell, unsigned int v16)
{
    unsigned int* w = tab + (cell >> 1);
    const int sh = (cell & 1) * 16;
    unsigned int old = *w;
    while (true) {
        const unsigned int cur = (old >> sh) & 0xFFFFu;
        if (cur >= v16) break;                       // current winner is later
        const unsigned int nw = (old & ~(0xFFFFu << sh)) | (v16 << sh);
        const unsigned int seen = atomicCAS(w, old, nw);
        if (seen == old) break;
        old = seen;                                  // contended: retry
    }
}

__global__ __launch_bounds__(256) void BondWeight_scatter_kernel(
    const float* __restrict__ weights,
    const int*   __restrict__ bsrc,
    const int*   __restrict__ bdst,
    const int*   __restrict__ btyp,
    float*       __restrict__ out)
{
    __shared__ unsigned int seqtab[CH_WORDS];
    __shared__ float s_wt[8];

    const int b  = blockIdx.x >> 2;                  // batch
    const int r0 = (blockIdx.x & 3) * CH_ROWS;       // row-chunk base
    const int t  = threadIdx.x;

    if (t < 8) s_wt[t] = weights[t];

    // zero the 32 KB table: uint4 x 8 per thread
    {
        uint4* tab4 = (uint4*)seqtab;
        #pragma unroll
        for (int k = 0; k < CH_WORDS / 4 / 256; ++k)
            tab4[t + 256 * k] = make_uint4(0u, 0u, 0u, 0u);
    }

    // My two edges -> four writes. seq order: pass1 (src,dst) e=0..511 then
    // pass2 (dst,src) e=0..511. packed = (seq+1)<<3 | type; max == last wins.
    const int ebase = b * NB_E;
    int row[4], col[4];
    unsigned int pk[4];
    #pragma unroll
    for (int i = 0; i < 2; ++i) {
        const int e  = t + 256 * i;
        const int s1 = bsrc[ebase + e] + 1;          // [1, 255]
        const int d1 = bdst[ebase + e] + 1;
        const unsigned int ty = (unsigned int)btyp[ebase + e] & 7u;
        row[2*i]   = s1; col[2*i]   = d1; pk[2*i]   = ((unsigned int)(e + 1) << 3) | ty;
        row[2*i+1] = d1; col[2*i+1] = s1; pk[2*i+1] = ((unsigned int)(NB_E + e + 1) << 3) | ty;
    }
    __syncthreads();                                 // table clean

    // CAS my in-chunk candidates
    #pragma unroll
    for (int i = 0; i < 4; ++i) {
        const int r = row[i] - r0;
        if (0 <= r && r < CH_ROWS)
            lds_max_u16(seqtab, r * NB_N + col[i], pk[i]);
    }
    __syncthreads();                                 // winners final

    // Readback: the thread whose pk survived owns the cell -> one dword store.
    float* __restrict__ ob = out + (size_t)b * (NB_N * NB_N);
    #pragma unroll
    for (int i = 0; i < 4; ++i) {
        const int r = row[i] - r0;
        if (0 <= r && r < CH_ROWS) {
            const int cell = r * NB_N + col[i];
            const unsigned int cur =
                (seqtab[cell >> 1] >> ((cell & 1) * 16)) & 0xFFFFu;
            if (cur == pk[i])                        // unique winner (pk unique)
                ob[(size_t)(r0 + r) * NB_N + col[i]] = s_wt[pk[i] & 7u];
        }
    }
}

extern "C" void kernel_launch(void* const* d_in, const int* in_sizes, int n_in,
                              void* d_out, int out_size, void* d_ws, size_t ws_size,
                              hipStream_t stream) {
    const float* weights = (const float*)d_in[0];   // [T=8]
    const int*   bsrc    = (const int*)d_in[1];     // [B, E]
    const int*   bdst    = (const int*)d_in[2];     // [B, E]
    const int*   btyp    = (const int*)d_in[3];     // [B, E]
    float*       out     = (float*)d_out;           // [B, N, N] f32

    const int nb = in_sizes[1] / NB_E;              // B = 1024
    const int total4 = nb * (NB_N * NB_N / 4);      // float4 count (16M)

    // A: zero-stream, fill-shaped (32 waves/CU). 2048 blocks -> 8 iters/thread.
    BondWeight_zero_kernel<<<2048, 256, 0, stream>>>(out, total4);

    // B: resolve + scatter winners. One block per (batch, 64-row chunk).
    BondWeight_scatter_kernel<<<nb * 4, 256, 0, stream>>>(
        weights, bsrc, bdst, btyp, out);
}

// Round 4
// 270.204 us; speedup vs baseline: 1.1667x; 1.1667x over previous
//
#include <hip/hip_runtime.h>

// BondWeight: out[b, src+1, dst+1] = w; out[b, dst+1, src+1] = w (two passes,
// last-write-wins within the 1024-write per-batch sequence, numpy semantics).
// B=1024, E=512, T=8, N=256. Output 256 MB f32 -> pure HBM-write-bound.
//
// Fused strategy (reverted to after R6's split regressed +46us: scattered
// dword overwrites caused partial-sector RMW traffic; single-pass streaming
// write is strictly better): per batch block, a u16 LDS table over a row
// chunk holds packed=(seq+1)<<3|type per cell; CAS-based 16-bit max gives
// last-write-wins; stream the chunk as coalesced float4 stores, re-zeroing
// the table on the fly. LDS-only barriers (R5) keep stores in flight.
//
// R7 change: OCCUPANCY. R4 (address phasing) and R5 (barrier store-drain)
// were exactly neutral -> last untested lever for the ~2.4x-over-floor
// store rate is per-CU write concurrency: the 6.4 TB/s fill runs 32
// waves/CU; our 32 KB table capped us at ~16 waves/CU. Halve the chunk:
// CH_ROWS=32 -> 16 KB LDS -> 8 blocks/CU = 32 waves/CU (the cap, matching
// the fill). __launch_bounds__(256,8) pins VGPR<=64 for 8 waves/SIMD.
// Cost: 8 chunks (8 extra lgkm barriers ~free per R5, CAS scan x2, trivial).
// PREDICTION: if concurrency was the wall, dur 268 -> ~225-235. If neutral
// again, kernel is at the write floor and the residual is harness overhead.

#define NB_E 512
#define NB_N 256
#define CH_ROWS 32
#define N_CHUNKS (NB_N / CH_ROWS)        // 8
#define CH_WORDS (CH_ROWS * NB_N / 2)    // 4096 u32 = 16 KB LDS
#define STREAM_IT ((CH_ROWS * NB_N / 4) / 256)  // 8 float4 per thread

typedef float v4f __attribute__((ext_vector_type(4)));

// LDS-only barrier: waits LDS ops, does NOT drain outstanding global stores.
__device__ __forceinline__ void barrier_lgkm()
{
    asm volatile("s_waitcnt lgkmcnt(0)" ::: "memory");
    __builtin_amdgcn_s_barrier();
}

__device__ __forceinline__ void lds_max_u16(unsigned int* tab, int cell, unsigned int v16)
{
    unsigned int* w = tab + (cell >> 1);
    const int sh = (cell & 1) * 16;
    unsigned int old = *w;
    while (true) {
        const unsigned int cur = (old >> sh) & 0xFFFFu;
        if (cur >= v16) break;                       // current winner is later
        const unsigned int nw = (old & ~(0xFFFFu << sh)) | (v16 << sh);
        const unsigned int seen = atomicCAS(w, old, nw);
        if (seen == old) break;
        old = seen;                                  // contended: retry
    }
}

__global__ __launch_bounds__(256, 8) void BondWeight_41738492182540_kernel(
    const float* __restrict__ weights,
    const int*   __restrict__ bsrc,
    const int*   __restrict__ bdst,
    const int*   __restrict__ btyp,
    float*       __restrict__ out)
{
    __shared__ unsigned int seqtab[CH_WORDS];
    __shared__ float s_wt[8];

    const int b = blockIdx.x;
    const int t = threadIdx.x;

    if (t < 8) s_wt[t] = weights[t];

    // My two edges -> four writes. seq order: pass1 (src,dst) e=0..511 then
    // pass2 (dst,src) e=0..511. packed = (seq+1)<<3 | type; max == last wins.
    const int ebase = b * NB_E;
    int row[4], col[4];
    unsigned int pk[4];
    #pragma unroll
    for (int i = 0; i < 2; ++i) {
        const int e  = t + 256 * i;
        const int s1 = bsrc[ebase + e] + 1;          // [1, 255]
        const int d1 = bdst[ebase + e] + 1;
        const unsigned int ty = (unsigned int)btyp[ebase + e] & 7u;
        row[2*i]   = s1; col[2*i]   = d1; pk[2*i]   = ((unsigned int)(e + 1) << 3) | ty;
        row[2*i+1] = d1; col[2*i+1] = s1; pk[2*i+1] = ((unsigned int)(NB_E + e + 1) << 3) | ty;
    }

    // --- zero the table ONCE: 4096 u32, uint4 x 4 per thread ---
    {
        uint4* tab4 = (uint4*)seqtab;
        #pragma unroll
        for (int k = 0; k < CH_WORDS / 4 / 256; ++k)
            tab4[t + 256 * k] = make_uint4(0u, 0u, 0u, 0u);
    }
    barrier_lgkm();

    float4* __restrict__ out4 = ((float4*)out) + (size_t)b * (NB_N * NB_N / 4);
    uint2*  __restrict__ tab2 = (uint2*)seqtab;

    const int crot = b & (N_CHUNKS - 1);             // chunk-order rotation
    const int krot = (b >> 3) & (STREAM_IT - 1);     // intra-chunk start rotation

    for (int cc = 0; cc < N_CHUNKS; ++cc) {
        const int r0 = ((cc + crot) & (N_CHUNKS - 1)) * CH_ROWS;

        // --- scatter my writes that land in this row chunk (table is clean) ---
        #pragma unroll
        for (int i = 0; i < 4; ++i) {
            const int r = row[i] - r0;
            if (0 <= r && r < CH_ROWS)
                lds_max_u16(seqtab, r * NB_N + col[i], pk[i]);
        }
        barrier_lgkm();   // CAS results visible; prior chunk's stores stay in flight

        // --- stream chunk: 2048 float4, 8/thread, coalesced; re-zero as we go ---
        #pragma unroll
        for (int j = 0; j < STREAM_IT; ++j) {
            const int i4 = t + 256 * ((j + krot) & (STREAM_IT - 1));
            const uint2 ab = tab2[i4];               // ds_read_b64
            tab2[i4] = make_uint2(0u, 0u);           // clean for next chunk's CAS
            v4f v;
            unsigned int p;
            p = ab.x & 0xFFFFu; v.x = p ? s_wt[p & 7u] : 0.0f;
            p = ab.x >> 16;     v.y = p ? s_wt[p & 7u] : 0.0f;
            p = ab.y & 0xFFFFu; v.z = p ? s_wt[p & 7u] : 0.0f;
            p = ab.y >> 16;     v.w = p ? s_wt[p & 7u] : 0.0f;
            *(v4f*)&out4[r0 * (NB_N / 4) + i4] = v;  // store queued; never drained in-loop
        }
        barrier_lgkm();   // rezero visible before next chunk's CAS; stores in flight
    }
    // kernel end: hardware completes outstanding stores at dispatch release
}

extern "C" void kernel_launch(void* const* d_in, const int* in_sizes, int n_in,
                              void* d_out, int out_size, void* d_ws, size_t ws_size,
                              hipStream_t stream) {
    const float* weights = (const float*)d_in[0];   // [T=8]
    const int*   bsrc    = (const int*)d_in[1];     // [B, E]
    const int*   bdst    = (const int*)d_in[2];     // [B, E]
    const int*   btyp    = (const int*)d_in[3];     // [B, E]
    float*       out     = (float*)d_out;           // [B, N, N] f32

    const int nb = in_sizes[1] / NB_E;              // B = 1024

    BondWeight_41738492182540_kernel<<<nb, 256, 0, stream>>>(
        weights, bsrc, bdst, btyp, out);
}